// Round 5
// baseline (12.710 us; speedup 1.0000x reference)
//
#include <hip/hip_runtime.h>

#define M_PTS 4096
#define N_NODES 1024
#define CAP 96   // per-wave compacted pairs: mean ~18 of 256 scanned, sigma ~4 -> 19-sigma margin

// RADIUS = 0.3, grid = linspace(-1.5,1.5,5), H = 0.75
#define INV_R (1.0f / 0.3f)
#define R2 (0.3f * 0.3f)
#define INV_H (4.0f / 3.0f)

__global__ __launch_bounds__(256) void kan_meshfree_kernel(
    const float* __restrict__ x,      // [M,2]
    const float* __restrict__ nodes,  // [N,2]
    const float* __restrict__ W1a,    // [HID,NUM]
    const float* __restrict__ W1b,    // [HID,NUM]
    const float* __restrict__ W2,     // [HID*NUM]
    const float* __restrict__ w,      // [N]
    float* __restrict__ u)            // [M]
{
    // per-wave compacted pair data: (d0, d1, bitcast(node index), pad)
    __shared__ float4 s_c[4][CAP];
    // layer-1 lerp tables: segment j (4), hidden h (8): (value_at_left_knot, delta)
    __shared__ float2 s_T1a[4][8];
    __shared__ float2 s_T1b[4][8];
    // layer-2 lerp table: knots k=0..6, zero-padded ends; stride 9 breaks bank aliasing
    __shared__ float2 s_T2[7][9];
    __shared__ float2 s_part[4];  // per-wave (S1,S2) partials

    const int tid = threadIdx.x;
    const int wave = tid >> 6;   // 0..3
    const int lane = tid & 63;
    const int m = blockIdx.x;    // ONE m-point per block, 4 waves cooperate

    // ---- issue tiny lerp-table builds (consumed only after the barrier below) ----
    if (tid < 32) {
        const int j = tid >> 3, h = tid & 7;
        const float a0 = W1a[h * 5 + j], a1 = W1a[h * 5 + j + 1];
        s_T1a[j][h] = make_float2(a0, a1 - a0);
        const float b0 = W1b[h * 5 + j], b1 = W1b[h * 5 + j + 1];
        s_T1b[j][h] = make_float2(b0, b1 - b0);
    } else if (tid < 32 + 56) {
        const int t = tid - 32;
        const int k = t >> 3, h = t & 7;  // k in 0..6
        const float q0 = (k >= 1 && k <= 5) ? W2[h * 5 + k - 1] : 0.f;
        const float q1 = (k + 1 <= 5) ? W2[h * 5 + k] : 0.f;
        s_T2[k][h] = make_float2(q0, q1 - q0);
    }

    const float2 xm = ((const float2*)x)[m];
    const float4* __restrict__ nodes4 = (const float4*)nodes;  // 2 nodes per element
    const unsigned long long lmask = (1ull << lane) - 1ull;

    // ---- phase 1: each wave scans its 256-node segment (2 iters, 2 nodes/lane) ----
    int cnt = 0;  // wave-uniform
#pragma unroll
    for (int it = 0; it < 2; ++it) {
        const int p = wave * 128 + it * 64 + lane;   // node-pair index
        const float4 nd = nodes4[p];
        const float d0a = xm.x - nd.x, d1a = xm.y - nd.y;
        const float d0b = xm.x - nd.z, d1b = xm.y - nd.w;
        const bool actA = fmaf(d0a, d0a, d1a * d1a) <= R2;
        const bool actB = fmaf(d0b, d0b, d1b * d1b) <= R2;
        const unsigned long long mA = __ballot(actA);
        if (actA) {
            const int pos = cnt + __popcll(mA & lmask);
            if (pos < CAP) s_c[wave][pos] = make_float4(d0a, d1a, __int_as_float(2 * p), 0.f);
        }
        cnt += __popcll(mA);
        const unsigned long long mB = __ballot(actB);
        if (actB) {
            const int pos = cnt + __popcll(mB & lmask);
            if (pos < CAP) s_c[wave][pos] = make_float4(d0b, d1b, __int_as_float(2 * p + 1), 0.f);
        }
        cnt += __popcll(mB);
    }
    if (cnt > CAP) cnt = CAP;

    // tables + own-wave s_c both visible after this (barrier implies LDS drain)
    __syncthreads();

    // ---- phase 2: KAN body on this wave's compacted pairs (cnt ~ 18 -> 1 iter) ----
    float S1 = 0.f, S2 = 0.f;
    for (int i = lane; i < cnt; i += 64) {
        const float4 c = s_c[wave][i];
        const float wn = w[__float_as_int(c.z)];  // issue early; hides under LDS chain
        const float d0 = c.x, d1 = c.y;
        const float dist2 = fmaf(d0, d0, d1 * d1);
        const float q2 = dist2 * (INV_R * INV_R);           // <= 1 guaranteed
        const float q = __builtin_amdgcn_sqrtf(q2);
        // win = 1 - 6q^2 + 8q^3 - 3q^4
        const float win = fmaf(q2, fmaf(q, fmaf(-3.f, q, 8.f), -6.f), 1.f);

        // layer-1 segment coords: t = d/R * (1/H) + 2  in [2/3, 10/3]
        const float ta = fmaf(d0 * INV_R, INV_H, 2.f);
        const float tb = fmaf(d1 * INV_R, INV_H, 2.f);
        const float fja = floorf(ta), fjb = floorf(tb);
        const float fa = ta - fja, fb = tb - fjb;
        const int ja = (int)fja, jb = (int)fjb;              // 0..3
        const float2* __restrict__ rowA = s_T1a[ja];
        const float2* __restrict__ rowB = s_T1b[jb];

        float phi = 0.f;
#pragma unroll
        for (int h = 0; h < 8; ++h) {
            const float2 A = rowA[h];
            const float2 B = rowB[h];
            const float hid = fmaf(fa, A.y, A.x) + fmaf(fb, B.y, B.x);
            // layer-2: t2 = (hid + 2.25)/H in [0,6] after clamp (table zero-padded)
            float t2 = fmaf(hid, INV_H, 3.f);
            t2 = fminf(fmaxf(t2, 0.f), 6.f);
            const float fj2 = floorf(t2);
            const float f2 = t2 - fj2;
            const int j2 = (int)fj2;                         // 0..6
            const float2 C = s_T2[j2][h];
            phi += fmaf(f2, C.y, C.x);
        }

        const float pw = phi * win;
        S1 += pw;
        S2 = fmaf(pw, wn, S2);
    }

    // wave butterfly reduction
#pragma unroll
    for (int off = 32; off >= 1; off >>= 1) {
        S1 += __shfl_down(S1, off);
        S2 += __shfl_down(S2, off);
    }

    if (lane == 0) s_part[wave] = make_float2(S1, S2);
    __syncthreads();

    if (tid == 0) {
        float a = 0.f, b = 0.f;
#pragma unroll
        for (int v = 0; v < 4; ++v) { a += s_part[v].x; b += s_part[v].y; }
        u[m] = b / (a + 1e-10f);
    }
}

extern "C" void kernel_launch(void* const* d_in, const int* in_sizes, int n_in,
                              void* d_out, int out_size, void* d_ws, size_t ws_size,
                              hipStream_t stream) {
    const float* x     = (const float*)d_in[0];
    const float* nodes = (const float*)d_in[1];
    const float* W1a   = (const float*)d_in[2];
    const float* W1b   = (const float*)d_in[3];
    const float* W2    = (const float*)d_in[4];
    const float* w     = (const float*)d_in[5];
    float* u = (float*)d_out;

    dim3 grid(M_PTS);   // one m-point per block, 4 cooperating waves
    dim3 block(256);
    hipLaunchKernelGGL(kan_meshfree_kernel, grid, block, 0, stream,
                       x, nodes, W1a, W1b, W2, w, u);
}

// Round 6
// 10.420 us; speedup vs baseline: 1.2198x; 1.2198x over previous
//
#include <hip/hip_runtime.h>

#define M_PTS 4096
#define N_NODES 1024
#define WAVES 16   // waves per block; 1 m-point per wave
#define CAP 128    // per-wave compacted pairs: mean ~72, binomial sigma ~8 -> 7-sigma margin

// RADIUS = 0.3, grid = linspace(-1.5,1.5,5), H = 0.75
#define INV_R (1.0f / 0.3f)
#define R2 (0.3f * 0.3f)
#define INV_H (4.0f / 3.0f)

__global__ __launch_bounds__(1024) void kan_meshfree_kernel(
    const float* __restrict__ x,      // [M,2]
    const float* __restrict__ nodes,  // [N,2]
    const float* __restrict__ W1a,    // [HID,NUM]
    const float* __restrict__ W1b,    // [HID,NUM]
    const float* __restrict__ W2,     // [HID*NUM]
    const float* __restrict__ w,      // [N]
    float* __restrict__ u)            // [M]
{
    // per-wave compacted pair data: (d0, d1, bitcast(node index), pad)
    __shared__ float4 s_c[WAVES][CAP];
    // layer-1 lerp tables: segment j (4), hidden h (8): (value_at_left_knot, delta)
    __shared__ float2 s_T1a[4][8];
    __shared__ float2 s_T1b[4][8];
    // layer-2 lerp table: knots k=0..6, zero-padded ends; stride 9 breaks bank aliasing
    __shared__ float2 s_T2[7][9];

    const int tid = threadIdx.x;
    const int wave = tid >> 6;   // 0..15
    const int lane = tid & 63;
    const int m = blockIdx.x * WAVES + wave;

    // ---- issue tiny lerp-table builds (waves 0-1); consumed after the barrier ----
    if (tid < 32) {
        const int j = tid >> 3, h = tid & 7;
        const float a0 = W1a[h * 5 + j], a1 = W1a[h * 5 + j + 1];
        s_T1a[j][h] = make_float2(a0, a1 - a0);
        const float b0 = W1b[h * 5 + j], b1 = W1b[h * 5 + j + 1];
        s_T1b[j][h] = make_float2(b0, b1 - b0);
    } else if (tid < 32 + 56) {
        const int t = tid - 32;
        const int k = t >> 3, h = t & 7;  // k in 0..6
        const float q0 = (k >= 1 && k <= 5) ? W2[h * 5 + k - 1] : 0.f;
        const float q1 = (k + 1 <= 5) ? W2[h * 5 + k] : 0.f;
        s_T2[k][h] = make_float2(q0, q1 - q0);
    }

    const float2 xm = ((const float2*)x)[m];
    const float4* __restrict__ nodes4 = (const float4*)nodes;  // 2 nodes per element
    const unsigned long long lmask = (1ull << lane) - 1ull;

    // ---- phase 1: scan all 1024 nodes, 2 per lane per iter (8 iters), compact ----
    int cnt = 0;  // wave-uniform
#pragma unroll
    for (int base = 0; base < N_NODES / 2; base += 64) {
        const int p = base + lane;          // node-pair index
        const float4 nd = nodes4[p];
        const float d0a = xm.x - nd.x, d1a = xm.y - nd.y;
        const float d0b = xm.x - nd.z, d1b = xm.y - nd.w;
        const bool actA = fmaf(d0a, d0a, d1a * d1a) <= R2;
        const bool actB = fmaf(d0b, d0b, d1b * d1b) <= R2;
        const unsigned long long mA = __ballot(actA);
        if (actA) {
            const int pos = cnt + __popcll(mA & lmask);
            if (pos < CAP) s_c[wave][pos] = make_float4(d0a, d1a, __int_as_float(2 * p), 0.f);
        }
        cnt += __popcll(mA);
        const unsigned long long mB = __ballot(actB);
        if (actB) {
            const int pos = cnt + __popcll(mB & lmask);
            if (pos < CAP) s_c[wave][pos] = make_float4(d0b, d1b, __int_as_float(2 * p + 1), 0.f);
        }
        cnt += __popcll(mB);
    }
    if (cnt > CAP) cnt = CAP;

    // tables visible + own-wave s_c drained after this barrier
    __syncthreads();

    // ---- phase 2: full-utilization KAN body on compacted pairs (~72 -> 2 iters) ----
    float S1 = 0.f, S2 = 0.f;
    for (int i = lane; i < cnt; i += 64) {
        const float4 c = s_c[wave][i];
        const float wn = w[__float_as_int(c.z)];  // issue early; hides under LDS chain
        const float d0 = c.x, d1 = c.y;
        const float dist2 = fmaf(d0, d0, d1 * d1);
        const float q2 = dist2 * (INV_R * INV_R);           // <= 1 guaranteed
        const float q = __builtin_amdgcn_sqrtf(q2);
        // win = 1 - 6q^2 + 8q^3 - 3q^4
        const float win = fmaf(q2, fmaf(q, fmaf(-3.f, q, 8.f), -6.f), 1.f);

        // layer-1 segment coords: t = d/R * (1/H) + 2  in [2/3, 10/3]
        const float ta = fmaf(d0 * INV_R, INV_H, 2.f);
        const float tb = fmaf(d1 * INV_R, INV_H, 2.f);
        const float fja = floorf(ta), fjb = floorf(tb);
        const float fa = ta - fja, fb = tb - fjb;
        const int ja = (int)fja, jb = (int)fjb;              // 0..3
        const float2* __restrict__ rowA = s_T1a[ja];
        const float2* __restrict__ rowB = s_T1b[jb];

        float phi = 0.f;
#pragma unroll
        for (int h = 0; h < 8; ++h) {
            const float2 A = rowA[h];
            const float2 B = rowB[h];
            const float hid = fmaf(fa, A.y, A.x) + fmaf(fb, B.y, B.x);
            // layer-2: t2 = (hid + 2.25)/H in [0,6] after clamp (table zero-padded)
            float t2 = fmaf(hid, INV_H, 3.f);
            t2 = fminf(fmaxf(t2, 0.f), 6.f);
            const float fj2 = floorf(t2);
            const float f2 = t2 - fj2;
            const int j2 = (int)fj2;                         // 0..6
            const float2 C = s_T2[j2][h];
            phi += fmaf(f2, C.y, C.x);
        }

        const float pw = phi * win;
        S1 += pw;
        S2 = fmaf(pw, wn, S2);
    }

    // wave butterfly reduction
#pragma unroll
    for (int off = 32; off >= 1; off >>= 1) {
        S1 += __shfl_down(S1, off);
        S2 += __shfl_down(S2, off);
    }

    if (lane == 0) u[m] = S2 / (S1 + 1e-10f);
}

extern "C" void kernel_launch(void* const* d_in, const int* in_sizes, int n_in,
                              void* d_out, int out_size, void* d_ws, size_t ws_size,
                              hipStream_t stream) {
    const float* x     = (const float*)d_in[0];
    const float* nodes = (const float*)d_in[1];
    const float* W1a   = (const float*)d_in[2];
    const float* W1b   = (const float*)d_in[3];
    const float* W2    = (const float*)d_in[4];
    const float* w     = (const float*)d_in[5];
    float* u = (float*)d_out;

    dim3 grid(M_PTS / WAVES);   // 256 workgroups, 16 waves each, 1 m per wave
    dim3 block(64 * WAVES);     // 1024 threads
    hipLaunchKernelGGL(kan_meshfree_kernel, grid, block, 0, stream,
                       x, nodes, W1a, W1b, W2, w, u);
}